// Round 1
// baseline (822.902 us; speedup 1.0000x reference)
//
#include <hip/hip_runtime.h>

// Axial multi-dimensional self-attention, B=1, C=32, D=32, H=128, W=128, fp32.
//
// Algebra: S_axis = X^T M X (M = scale * Wq^T Wk), A = softmax_rows(S),
//          U_axis = X A^T, out = P (U_D + U_H + U_W) + x, P = Wo Wv.
// U accumulates directly in d_out; epilogue transforms in place. No ws use.

#define C_ 32
#define D_ 32
#define H_ 128
#define W_ 128
#define SC (D_*H_*W_)   // 524288 channel stride (floats)
#define SD (H_*W_)      // 16384
#define SH (W_)         // 128
#define SCALE 0.17677669529663687f  // 32^-0.5

// chunked XCD swizzle: consecutive logical ids land on the same XCD
// (valid: all grids are multiples of 8)
__device__ __forceinline__ int xcd_swz(int bid, int nwg) {
    int chunk = nwg >> 3;
    return (bid & 7) * chunk + (bid >> 3);
}

// M[c][c2] = SCALE * sum_o Wq[o][c] * Wk[o][c2]  (weights are [o][c] row-major)
__device__ __forceinline__ void compute_M(const float* __restrict__ Wq,
                                          const float* __restrict__ Wk,
                                          float* Ms) {
    for (int o = threadIdx.x; o < 1024; o += 256) {
        int c = o >> 5, c2 = o & 31;
        float acc = 0.f;
        #pragma unroll
        for (int m = 0; m < 32; ++m) acc += Wq[m*32+c] * Wk[m*32+c2];
        Ms[o] = acc * SCALE;
    }
}

// ---------------- W-axis attention: slices (d,h), L=128, native coalescing ---
__global__ __launch_bounds__(256) void kw_kernel(const float* __restrict__ x,
        const float* __restrict__ Wq, const float* __restrict__ Wk,
        float* __restrict__ U) {
    __shared__ float Xs[C_*W_];   // [c][u] 16KB
    __shared__ float Ts[C_*W_];   // [c][u] 16KB
    __shared__ float Ms[C_*C_];   // 4KB
    int bid = xcd_swz(blockIdx.x, gridDim.x);
    int d = bid >> 7, h = bid & 127;
    int t = threadIdx.x;
    compute_M(Wq, Wk, Ms);
    const float* xs = x + d*SD + h*SH;
    for (int o = t; o < C_*W_/4; o += 256) {          // coalesced float4 loads
        int c = o >> 5, u4 = o & 31;
        float4 v = *reinterpret_cast<const float4*>(xs + c*SC + u4*4);
        *reinterpret_cast<float4*>(&Xs[c*W_ + u4*4]) = v;
    }
    __syncthreads();
    // T = M * X
    for (int o = t; o < C_*W_; o += 256) {
        int c = o >> 7, u = o & 127;
        float acc = 0.f;
        #pragma unroll
        for (int c2 = 0; c2 < 32; ++c2) acc += Ms[c*32+c2] * Xs[c2*W_+u];
        Ts[o] = acc;
    }
    __syncthreads();
    // 2 threads per query row q (=w), each owns 64 key columns
    int q = t >> 1, p = t & 1;
    float s[64];
    #pragma unroll
    for (int u = 0; u < 64; ++u) s[u] = 0.f;
    for (int c = 0; c < 32; ++c) {
        float xc = Xs[c*W_ + q];
        const float4* tr = reinterpret_cast<const float4*>(&Ts[c*W_ + p*64]);
        #pragma unroll
        for (int u4 = 0; u4 < 16; ++u4) {
            float4 tv = tr[u4];
            s[u4*4+0] += xc*tv.x; s[u4*4+1] += xc*tv.y;
            s[u4*4+2] += xc*tv.z; s[u4*4+3] += xc*tv.w;
        }
    }
    float m = -1e30f;
    #pragma unroll
    for (int u = 0; u < 64; ++u) m = fmaxf(m, s[u]);
    m = fmaxf(m, __shfl_xor(m, 1));
    float l = 0.f;
    #pragma unroll
    for (int u = 0; u < 64; ++u) { float e = __expf(s[u]-m); s[u] = e; l += e; }
    l += __shfl_xor(l, 1);
    float rl = 1.f / l;
    // U[c][q] = (1/l) * sum_u e[u] * X[c][u]; pair-combined, even lane stores
    float* Uout = U + d*SD + h*SH + q;
    for (int c = 0; c < 32; ++c) {
        const float4* xr = reinterpret_cast<const float4*>(&Xs[c*W_ + p*64]);
        float acc = 0.f;
        #pragma unroll
        for (int u4 = 0; u4 < 16; ++u4) {
            float4 xv = xr[u4];
            acc += s[u4*4+0]*xv.x + s[u4*4+1]*xv.y
                 + s[u4*4+2]*xv.z + s[u4*4+3]*xv.w;
        }
        float v = (acc + __shfl_xor(acc, 1)) * rl;
        if (p == 0) Uout[c*SC] = v;   // first axis: plain store (full coverage)
    }
}

// ---------------- H-axis attention: slices (d,w), L=128, w-pair tiling -------
__global__ __launch_bounds__(256) void kh_kernel(const float* __restrict__ x,
        const float* __restrict__ Wq, const float* __restrict__ Wk,
        float* __restrict__ U) {
    __shared__ float Xs0[C_*H_];  // slice j=0, [c][g]
    __shared__ float Xs1[C_*H_];  // slice j=1
    __shared__ float Ts[C_*H_];
    __shared__ float Ms[C_*C_];
    int bid = xcd_swz(blockIdx.x, gridDim.x);   // same-d siblings share an XCD
    int d = bid >> 6, w0 = (bid & 63) * 2;
    int t = threadIdx.x;
    compute_M(Wq, Wk, Ms);
    const float* xs = x + d*SD + w0;
    for (int o = t; o < C_*H_; o += 256) {      // float2 per (c,g): 8B granules
        int c = o >> 7, g = o & 127;
        float2 v = *reinterpret_cast<const float2*>(xs + c*SC + g*SH);
        Xs0[c*H_+g] = v.x;
        Xs1[c*H_+g] = v.y;
    }
    __syncthreads();
    int q = t >> 1, p = t & 1;
    #pragma unroll
    for (int j = 0; j < 2; ++j) {
        const float* Xj = j ? Xs1 : Xs0;
        for (int o = t; o < C_*H_; o += 256) {
            int c = o >> 7, g = o & 127;
            float acc = 0.f;
            #pragma unroll
            for (int c2 = 0; c2 < 32; ++c2) acc += Ms[c*32+c2] * Xj[c2*H_+g];
            Ts[o] = acc;
        }
        __syncthreads();
        float s[64];
        #pragma unroll
        for (int u = 0; u < 64; ++u) s[u] = 0.f;
        for (int c = 0; c < 32; ++c) {
            float xc = Xj[c*H_ + q];
            const float4* tr = reinterpret_cast<const float4*>(&Ts[c*H_ + p*64]);
            #pragma unroll
            for (int u4 = 0; u4 < 16; ++u4) {
                float4 tv = tr[u4];
                s[u4*4+0] += xc*tv.x; s[u4*4+1] += xc*tv.y;
                s[u4*4+2] += xc*tv.z; s[u4*4+3] += xc*tv.w;
            }
        }
        float m = -1e30f;
        #pragma unroll
        for (int u = 0; u < 64; ++u) m = fmaxf(m, s[u]);
        m = fmaxf(m, __shfl_xor(m, 1));
        float l = 0.f;
        #pragma unroll
        for (int u = 0; u < 64; ++u) { float e = __expf(s[u]-m); s[u] = e; l += e; }
        l += __shfl_xor(l, 1);
        float rl = 1.f / l;
        float* Uout = U + d*SD + q*SH + w0 + j;   // q is the h row
        for (int c = 0; c < 32; ++c) {
            const float4* xr = reinterpret_cast<const float4*>(&Xj[c*H_ + p*64]);
            float acc = 0.f;
            #pragma unroll
            for (int u4 = 0; u4 < 16; ++u4) {
                float4 xv = xr[u4];
                acc += s[u4*4+0]*xv.x + s[u4*4+1]*xv.y
                     + s[u4*4+2]*xv.z + s[u4*4+3]*xv.w;
            }
            float v = (acc + __shfl_xor(acc, 1)) * rl;
            if (p == 0) Uout[c*SC] += v;          // accumulate (L2-merged RMW)
        }
        __syncthreads();   // protect Ts overwrite for next j
    }
}

// ---------------- D-axis attention: slices (h,w), L=32, 8 slices/block -------
#define PD 1032   // padded [c][e] plane (32*32 + 8) so per-j float4 reads spread banks
__global__ __launch_bounds__(256) void kd_kernel(const float* __restrict__ x,
        const float* __restrict__ Wq, const float* __restrict__ Wk,
        float* __restrict__ U) {
    __shared__ float Xs[8*PD];   // [j][c][e] ~33KB
    __shared__ float Ts[8*PD];
    __shared__ float Ms[C_*C_];
    int bid = xcd_swz(blockIdx.x, gridDim.x);
    int h = bid >> 4, w0 = (bid & 15) * 8;
    int t = threadIdx.x;
    compute_M(Wq, Wk, Ms);
    const float* xs = x + h*SH + w0;
    for (int o = t; o < 2048; o += 256) {        // float4 over w-halves
        int j4 = o & 1, dd = (o >> 1) & 31, c = o >> 6;
        float4 v = *reinterpret_cast<const float4*>(xs + c*SC + dd*SD + j4*4);
        int base = c*32 + dd;
        Xs[(j4*4+0)*PD + base] = v.x;
        Xs[(j4*4+1)*PD + base] = v.y;
        Xs[(j4*4+2)*PD + base] = v.z;
        Xs[(j4*4+3)*PD + base] = v.w;
    }
    __syncthreads();
    for (int o = t; o < 8192; o += 256) {        // T = M*X per slice plane
        int j = o >> 10, r = o & 1023, c = r >> 5, e = r & 31;
        float acc = 0.f;
        #pragma unroll
        for (int c2 = 0; c2 < 32; ++c2) acc += Ms[c*32+c2] * Xs[j*PD + c2*32 + e];
        Ts[j*PD + c*32 + e] = acc;
    }
    __syncthreads();
    int j = t & 7, q = t >> 3;   // thread owns full row q of slice j
    float s[32];
    #pragma unroll
    for (int e = 0; e < 32; ++e) s[e] = 0.f;
    for (int c = 0; c < 32; ++c) {
        float xc = Xs[j*PD + c*32 + q];
        const float4* tr = reinterpret_cast<const float4*>(&Ts[j*PD + c*32]);
        #pragma unroll
        for (int e4 = 0; e4 < 8; ++e4) {
            float4 tv = tr[e4];
            s[e4*4+0] += xc*tv.x; s[e4*4+1] += xc*tv.y;
            s[e4*4+2] += xc*tv.z; s[e4*4+3] += xc*tv.w;
        }
    }
    float m = -1e30f;
    #pragma unroll
    for (int e = 0; e < 32; ++e) m = fmaxf(m, s[e]);
    float l = 0.f;
    #pragma unroll
    for (int e = 0; e < 32; ++e) { float ee = __expf(s[e]-m); s[e] = ee; l += ee; }
    float rl = 1.f / l;
    float* Uout = U + q*SD + h*SH + w0 + j;      // q is the d row
    for (int c = 0; c < 32; ++c) {
        const float4* xr = reinterpret_cast<const float4*>(&Xs[j*PD + c*32]);
        float acc = 0.f;
        #pragma unroll
        for (int e4 = 0; e4 < 8; ++e4) {
            float4 xv = xr[e4];
            acc += s[e4*4+0]*xv.x + s[e4*4+1]*xv.y
                 + s[e4*4+2]*xv.z + s[e4*4+3]*xv.w;
        }
        Uout[c*SC] += acc * rl;                   // accumulate (32B clusters)
    }
}

// ---------------- epilogue: out = P*U + x, in place on d_out -----------------
__global__ __launch_bounds__(256) void ko_kernel(const float* __restrict__ x,
        const float* __restrict__ Wv, const float* __restrict__ Wo,
        float* UO) {
    __shared__ float Ps[1024];   // P = Wo*Wv
    int t = threadIdx.x;
    for (int o = t; o < 1024; o += 256) {
        int oo = o >> 5, c = o & 31;
        float acc = 0.f;
        #pragma unroll
        for (int m = 0; m < 32; ++m) acc += Wo[oo*32+m] * Wv[m*32+c];
        Ps[o] = acc;
    }
    __syncthreads();
    int s = blockIdx.x * 256 + t;   // one spatial site per thread, lane -> w
    float u[32];
    #pragma unroll
    for (int c = 0; c < 32; ++c) u[c] = UO[c*SC + s];
    for (int oo = 0; oo < 32; ++oo) {
        float acc = x[oo*SC + s];
        #pragma unroll
        for (int c = 0; c < 32; ++c) acc += Ps[oo*32+c] * u[c];
        UO[oo*SC + s] = acc;
    }
}

extern "C" void kernel_launch(void* const* d_in, const int* in_sizes, int n_in,
                              void* d_out, int out_size, void* d_ws, size_t ws_size,
                              hipStream_t stream) {
    (void)in_sizes; (void)n_in; (void)out_size; (void)d_ws; (void)ws_size;
    const float* x  = (const float*)d_in[0];
    const float* Wq = (const float*)d_in[1];
    const float* Wk = (const float*)d_in[2];
    const float* Wv = (const float*)d_in[3];
    const float* Wo = (const float*)d_in[4];
    float* U = (float*)d_out;
    kw_kernel<<<dim3(4096), dim3(256), 0, stream>>>(x, Wq, Wk, U);  // writes U
    kh_kernel<<<dim3(2048), dim3(256), 0, stream>>>(x, Wq, Wk, U);  // U +=
    kd_kernel<<<dim3(2048), dim3(256), 0, stream>>>(x, Wq, Wk, U);  // U +=
    ko_kernel<<<dim3(2048), dim3(256), 0, stream>>>(x, Wv, Wo, U);  // in-place
}

// Round 5
// 431.567 us; speedup vs baseline: 1.9068x; 1.9068x over previous
//
#include <hip/hip_runtime.h>

// Axial multi-dimensional self-attention, B=1, C=32, D=32, H=128, W=128, fp32.
// Algebra: S = X^T M X (M = scale*Wq^T*Wk), P = softmax_rows(S), U = X P^T,
//          out = (Wo Wv) (U_D + U_H + U_W) + x.
// kw/kh: MFMA slice engine (split-bf16 scores, bf16 P). kd: fp32 VALU (L=32)
// fused with the output projection + residual.

#define C_ 32
#define D_ 32
#define H_ 128
#define W_ 128
#define SC (D_*H_*W_)   // 524288
#define SD (H_*W_)      // 16384
#define SH (W_)         // 128
#define SCALE 0.17677669529663687f

typedef __attribute__((ext_vector_type(8))) short short8;   // 8 bf16 (4 VGPR)
typedef __attribute__((ext_vector_type(2))) short short2v;  // 2 bf16
typedef __attribute__((ext_vector_type(4))) float f32x4;

#define MFMA16(a,b,c) __builtin_amdgcn_mfma_f32_16x16x32_bf16(a,b,c,0,0,0)

__device__ __forceinline__ int xcd_swz(int bid, int nwg) {
    int chunk = nwg >> 3;
    return (bid & 7) * chunk + (bid >> 3);
}
__device__ __forceinline__ short bf16_trunc(float f) {
    return (short)(__float_as_uint(f) >> 16);
}
__device__ __forceinline__ short bf16_rtne(float f) {
    unsigned u = __float_as_uint(f);
    unsigned r = u + 0x7FFFu + ((u >> 16) & 1u);
    return (short)(r >> 16);
}
__device__ __forceinline__ float bf16_tof(short s) {
    return __uint_as_float(((unsigned)(unsigned short)s) << 16);
}

// fp32 M (kd): M[a][b] = SCALE * sum_o Wq[o][a]*Wk[o][b]
__device__ __forceinline__ void compute_M(const float* __restrict__ Wq,
                                          const float* __restrict__ Wk,
                                          float* Ms) {
    for (int o = threadIdx.x; o < 1024; o += 256) {
        int a = o >> 5, b = o & 31;
        float acc = 0.f;
        #pragma unroll
        for (int m = 0; m < 32; ++m) acc += Wq[m*32+a] * Wk[m*32+b];
        Ms[o] = acc * SCALE;
    }
}
// split-bf16 M (kw/kh)
__device__ __forceinline__ void compute_Mbf(const float* __restrict__ Wq,
                                            const float* __restrict__ Wk,
                                            short* Mh, short* Ml) {
    for (int o = threadIdx.x; o < 1024; o += 256) {
        int a = o >> 5, b = o & 31;
        float acc = 0.f;
        #pragma unroll
        for (int m = 0; m < 32; ++m) acc += Wq[m*32+a] * Wk[m*32+b];
        acc *= SCALE;
        short h = bf16_trunc(acc);
        Mh[o] = h;
        Ml[o] = bf16_trunc(acc - bf16_tof(h));
    }
}

// ---------------- MFMA slice engine: one L=128 slice -------------------------
// LDS R region (36864 B) = [Xf fp32 32x128 | Tt_h 128x40 | Tt_l 128x40],
// later overlaid by P bf16 [128][136] (34816 B). Xh bf16 [32][136] separate.
// TT_STRIDE=40 shorts = 80 B rows: keeps every short8 read 16 B-aligned
// (ds_read_b128 needs natural alignment) and bank-start (20r+4hi)%32 repeats
// only at r vs r+8 -> <=2-way (free per m136).
#define TT_STRIDE 40
#define XH_STRIDE 136    // 272 B rows: 16-aligned, 4-bank stride, 2-way max
#define P_STRIDE  136
#define R_BYTES   36864

__device__ __forceinline__ void slice_engine(
        const float* Xf, const short* Mh, const short* Ml,
        short* Tt_h, short* Tt_l, short* P, short* Xh,
        f32x4 uacc[2][2])
{
    const int t = threadIdx.x;
    const int wv = t >> 6, l = t & 63, hi = l >> 4, r = l & 15;
    const int qb = wv * 32;

    // Xh (row-major bf16, RTNE) from Xf — consumed by the U phase
    #pragma unroll
    for (int k = 0; k < 8; ++k) {
        int idx = t + k*256;
        int u2 = idx & 63, c = idx >> 6;
        float2 v = *(const float2*)&Xf[c*128 + u2*2];
        short2v h; h[0] = bf16_rtne(v.x); h[1] = bf16_rtne(v.y);
        *(short2v*)&Xh[c*XH_STRIDE + u2*2] = h;
    }

    // Split-bf16 X column fragments for this wave's 32 columns.
    // Same lane layout as MFMA-B (k=c, col=u) in T=M*X and as
    // MFMA-A (row=q, k=c) in S=X^T*T — build once, use twice.
    short8 xh_[2], xl_[2];
    #pragma unroll
    for (int nt = 0; nt < 2; ++nt) {
        int u = qb + nt*16 + r;
        #pragma unroll
        for (int j = 0; j < 8; ++j) {
            float f = Xf[(hi*8 + j)*128 + u];
            short h = bf16_trunc(f);
            xh_[nt][j] = h; xl_[nt][j] = bf16_trunc(f - bf16_tof(h));
        }
    }

    // ---- T = M*X (3-MFMA split); wave owns u-range [qb, qb+32) ----
    short8 mah[2], mal[2];
    #pragma unroll
    for (int mt = 0; mt < 2; ++mt) {
        mah[mt] = *(const short8*)&Mh[(r + 16*mt)*32 + hi*8];
        mal[mt] = *(const short8*)&Ml[(r + 16*mt)*32 + hi*8];
    }
    f32x4 tacc[2][2] = {};
    #pragma unroll
    for (int nt = 0; nt < 2; ++nt) {
        #pragma unroll
        for (int mt = 0; mt < 2; ++mt) {
            tacc[mt][nt] = MFMA16(mah[mt], xh_[nt], tacc[mt][nt]);
            tacc[mt][nt] = MFMA16(mah[mt], xl_[nt], tacc[mt][nt]);
            tacc[mt][nt] = MFMA16(mal[mt], xh_[nt], tacc[mt][nt]);
        }
    }
    // write T transposed + split: Tt[u][c]
    #pragma unroll
    for (int mt = 0; mt < 2; ++mt)
    #pragma unroll
    for (int nt = 0; nt < 2; ++nt) {
        int u = qb + nt*16 + r;
        #pragma unroll
        for (int rp = 0; rp < 2; ++rp) {
            int c0 = 16*mt + 4*hi + 2*rp;
            float f0 = tacc[mt][nt][2*rp], f1 = tacc[mt][nt][2*rp+1];
            short h0 = bf16_trunc(f0), h1 = bf16_trunc(f1);
            short2v vh; vh[0] = h0; vh[1] = h1;
            *(short2v*)&Tt_h[u*TT_STRIDE + c0] = vh;
            short2v vl; vl[0] = bf16_trunc(f0 - bf16_tof(h0));
            vl[1] = bf16_trunc(f1 - bf16_tof(h1));
            *(short2v*)&Tt_l[u*TT_STRIDE + c0] = vl;
        }
    }
    __syncthreads();

    // ---- S = X^T T (3-MFMA split); wave owns q-stripe [qb, qb+32) ----
    f32x4 sacc[2][8] = {};
    #pragma unroll
    for (int nt = 0; nt < 8; ++nt) {
        short8 th = *(const short8*)&Tt_h[(nt*16 + r)*TT_STRIDE + hi*8];
        short8 tl = *(const short8*)&Tt_l[(nt*16 + r)*TT_STRIDE + hi*8];
        #pragma unroll
        for (int qt = 0; qt < 2; ++qt) {
            sacc[qt][nt] = MFMA16(xh_[qt], th, sacc[qt][nt]);
            sacc[qt][nt] = MFMA16(xh_[qt], tl, sacc[qt][nt]);
            sacc[qt][nt] = MFMA16(xl_[qt], th, sacc[qt][nt]);
        }
    }
    // ---- softmax over u (D-layout: row q = qb+16qt+4hi+reg, col u = 16nt+r)
    float rls[2][4];
    #pragma unroll
    for (int qt = 0; qt < 2; ++qt)
    #pragma unroll
    for (int reg = 0; reg < 4; ++reg) {
        float m = sacc[qt][0][reg];
        #pragma unroll
        for (int nt = 1; nt < 8; ++nt) m = fmaxf(m, sacc[qt][nt][reg]);
        m = fmaxf(m, __shfl_xor(m, 1));
        m = fmaxf(m, __shfl_xor(m, 2));
        m = fmaxf(m, __shfl_xor(m, 4));
        m = fmaxf(m, __shfl_xor(m, 8));
        float s = 0.f;
        #pragma unroll
        for (int nt = 0; nt < 8; ++nt) {
            float e = __expf(sacc[qt][nt][reg] - m);
            sacc[qt][nt][reg] = e; s += e;
        }
        s += __shfl_xor(s, 1);
        s += __shfl_xor(s, 2);
        s += __shfl_xor(s, 4);
        s += __shfl_xor(s, 8);
        rls[qt][reg] = 1.f / s;
    }
    __syncthreads();                 // all Tt/Xf reads done -> safe to overlay P
    #pragma unroll
    for (int qt = 0; qt < 2; ++qt)
    #pragma unroll
    for (int reg = 0; reg < 4; ++reg) {
        int q = qb + 16*qt + 4*hi + reg;
        float rl = rls[qt][reg];
        #pragma unroll
        for (int nt = 0; nt < 8; ++nt)
            P[q*P_STRIDE + nt*16 + r] = bf16_rtne(sacc[qt][nt][reg] * rl);
    }
    __syncthreads();

    // ---- U = Xh * P^T : wave computes U[:, its 32 q] ----
    #pragma unroll
    for (int kt = 0; kt < 4; ++kt) {
        short8 xa[2], pb[2];
        #pragma unroll
        for (int mt = 0; mt < 2; ++mt)
            xa[mt] = *(const short8*)&Xh[(r + 16*mt)*XH_STRIDE + hi*8 + kt*32];
        #pragma unroll
        for (int nt = 0; nt < 2; ++nt)
            pb[nt] = *(const short8*)&P[(qb + 16*nt + r)*P_STRIDE + hi*8 + kt*32];
        #pragma unroll
        for (int mt = 0; mt < 2; ++mt)
        #pragma unroll
        for (int nt = 0; nt < 2; ++nt)
            uacc[mt][nt] = MFMA16(xa[mt], pb[nt], uacc[mt][nt]);
    }
}

// ---------------- W-axis: slice (d,h), coalesced ----------------------------
__global__ __launch_bounds__(256) void kw_kernel(const float* __restrict__ x,
        const float* __restrict__ Wq, const float* __restrict__ Wk,
        float* __restrict__ U) {
    __shared__ __align__(16) char Rr[R_BYTES];
    __shared__ __align__(16) short Xh[32*XH_STRIDE];
    __shared__ __align__(16) short MhS[1024], MlS[1024];
    float* Xf = (float*)Rr;
    short* Tt_h = (short*)(Rr + 16384);
    short* Tt_l = (short*)(Rr + 26624);
    short* P = (short*)Rr;
    int bid = xcd_swz(blockIdx.x, gridDim.x);
    int d = bid >> 7, h = bid & 127;
    int t = threadIdx.x;
    compute_Mbf(Wq, Wk, MhS, MlS);
    const float* xs = x + d*SD + h*SH;
    #pragma unroll
    for (int k = 0; k < 4; ++k) {
        int idx = t + k*256;
        int c = idx >> 5, u4 = idx & 31;
        *(float4*)&Xf[c*128 + u4*4] = *(const float4*)&xs[c*SC + u4*4];
    }
    __syncthreads();
    f32x4 uacc[2][2] = {};
    slice_engine(Xf, MhS, MlS, Tt_h, Tt_l, P, Xh, uacc);
    const int wv = t >> 6, l = t & 63, hi = l >> 4, r = l & 15;
    float* Uo = U + d*SD + h*SH;
    #pragma unroll
    for (int mt = 0; mt < 2; ++mt)
    #pragma unroll
    for (int nt = 0; nt < 2; ++nt)
    #pragma unroll
    for (int reg = 0; reg < 4; ++reg) {
        int c = 16*mt + 4*hi + reg;
        int q = wv*32 + 16*nt + r;
        Uo[c*SC + q] = uacc[mt][nt][reg];   // first axis: plain store
    }
}

// ---------------- H-axis: slices (d, w-pair) --------------------------------
__global__ __launch_bounds__(256) void kh_kernel(const float* __restrict__ x,
        const float* __restrict__ Wq, const float* __restrict__ Wk,
        float* __restrict__ U) {
    __shared__ __align__(16) char Rr[R_BYTES];
    __shared__ __align__(16) float Xf1[32*128];
    __shared__ __align__(16) short Xh[32*XH_STRIDE];
    __shared__ __align__(16) short MhS[1024], MlS[1024];
    float* Xf0 = (float*)Rr;
    short* Tt_h = (short*)(Rr + 16384);
    short* Tt_l = (short*)(Rr + 26624);
    short* P = (short*)Rr;
    int bid = xcd_swz(blockIdx.x, gridDim.x);   // same-d siblings share an XCD
    int d = bid >> 6, w0 = (bid & 63) * 2;
    int t = threadIdx.x;
    compute_Mbf(Wq, Wk, MhS, MlS);
    const float* xs = x + d*SD + w0;
    #pragma unroll
    for (int k = 0; k < 16; ++k) {
        int idx = t + k*256;
        int c = idx >> 7, g = idx & 127;
        float2 v = *(const float2*)&xs[c*SC + g*SH];
        Xf0[c*128+g] = v.x;
        Xf1[c*128+g] = v.y;
    }
    __syncthreads();
    f32x4 u0[2][2] = {}, u1[2][2] = {};
    slice_engine(Xf0, MhS, MlS, Tt_h, Tt_l, P, Xh, u0);
    __syncthreads();   // protect R-region / Xh reuse by slice 1
    slice_engine(Xf1, MhS, MlS, Tt_h, Tt_l, P, Xh, u1);
    const int wv = t >> 6, l = t & 63, hi = l >> 4, r = l & 15;
    float* Uo = U + d*SD + w0;
    #pragma unroll
    for (int mt = 0; mt < 2; ++mt)
    #pragma unroll
    for (int nt = 0; nt < 2; ++nt)
    #pragma unroll
    for (int reg = 0; reg < 4; ++reg) {
        int c = 16*mt + 4*hi + reg;
        int q = wv*32 + 16*nt + r;     // q is the h row
        float2* p = (float2*)&Uo[c*SC + q*SH];
        float2 v = *p;
        v.x += u0[mt][nt][reg];
        v.y += u1[mt][nt][reg];
        *p = v;
    }
}

// ---------------- D-axis (L=32, fp32) fused with projection epilogue --------
#define PD 1032
__global__ __launch_bounds__(256) void kd_kernel(const float* __restrict__ x,
        const float* __restrict__ Wq, const float* __restrict__ Wk,
        const float* __restrict__ Wv, const float* __restrict__ Wo,
        float* UO) {
    __shared__ float Xs[8*PD];
    __shared__ float Ts[8*PD];
    __shared__ float Ms[1024];
    __shared__ float Ps[32*33];
    int bid = xcd_swz(blockIdx.x, gridDim.x);
    int h = bid >> 4, w0 = (bid & 15) * 8;
    int t = threadIdx.x;
    compute_M(Wq, Wk, Ms);
    for (int o = t; o < 1024; o += 256) {     // Ps = Wo*Wv
        int oo = o >> 5, c = o & 31;
        float acc = 0.f;
        #pragma unroll
        for (int m = 0; m < 32; ++m) acc += Wo[oo*32+m] * Wv[m*32+c];
        Ps[oo*33+c] = acc;
    }
    const float* xs = x + h*SH + w0;
    for (int o = t; o < 2048; o += 256) {
        int j4 = o & 1, dd = (o >> 1) & 31, c = o >> 6;
        float4 v = *reinterpret_cast<const float4*>(xs + c*SC + dd*SD + j4*4);
        int base = c*32 + dd;
        Xs[(j4*4+0)*PD + base] = v.x;
        Xs[(j4*4+1)*PD + base] = v.y;
        Xs[(j4*4+2)*PD + base] = v.z;
        Xs[(j4*4+3)*PD + base] = v.w;
    }
    __syncthreads();
    for (int o = t; o < 8192; o += 256) {
        int j = o >> 10, rr = o & 1023, c = rr >> 5, e = rr & 31;
        float acc = 0.f;
        #pragma unroll
        for (int c2 = 0; c2 < 32; ++c2) acc += Ms[c*32+c2] * Xs[j*PD + c2*32 + e];
        Ts[j*PD + c*32 + e] = acc;
    }
    __syncthreads();
    int j = t & 7, q = t >> 3;
    float s[32];
    #pragma unroll
    for (int e = 0; e < 32; ++e) s[e] = 0.f;
    for (int c = 0; c < 32; ++c) {
        float xc = Xs[j*PD + c*32 + q];
        const float4* tr = reinterpret_cast<const float4*>(&Ts[j*PD + c*32]);
        #pragma unroll
        for (int e4 = 0; e4 < 8; ++e4) {
            float4 tv = tr[e4];
            s[e4*4+0] += xc*tv.x; s[e4*4+1] += xc*tv.y;
            s[e4*4+2] += xc*tv.z; s[e4*4+3] += xc*tv.w;
        }
    }
    float m = -1e30f;
    #pragma unroll
    for (int e = 0; e < 32; ++e) m = fmaxf(m, s[e]);
    float l = 0.f;
    #pragma unroll
    for (int e = 0; e < 32; ++e) { float ee = __expf(s[e]-m); s[e] = ee; l += ee; }
    float rl = 1.f / l;
    int site = q*SD + h*SH + w0 + j;          // q is the d row
    float u[32];
    for (int c = 0; c < 32; ++c) {
        const float4* xr = reinterpret_cast<const float4*>(&Xs[j*PD + c*32]);
        float acc = 0.f;
        #pragma unroll
        for (int e4 = 0; e4 < 8; ++e4) {
            float4 xv = xr[e4];
            acc += s[e4*4+0]*xv.x + s[e4*4+1]*xv.y
                 + s[e4*4+2]*xv.z + s[e4*4+3]*xv.w;
        }
        u[c] = UO[site + c*SC] + acc * rl;    // final U for this site
    }
    #pragma unroll
    for (int o = 0; o < 32; ++o) {            // out = Ps*u + x (in place)
        float acc = x[site + o*SC];
        #pragma unroll
        for (int c = 0; c < 32; ++c) acc += Ps[o*33+c] * u[c];
        UO[site + o*SC] = acc;
    }
}

extern "C" void kernel_launch(void* const* d_in, const int* in_sizes, int n_in,
                              void* d_out, int out_size, void* d_ws, size_t ws_size,
                              hipStream_t stream) {
    (void)in_sizes; (void)n_in; (void)out_size; (void)d_ws; (void)ws_size;
    const float* x  = (const float*)d_in[0];
    const float* Wq = (const float*)d_in[1];
    const float* Wk = (const float*)d_in[2];
    const float* Wv = (const float*)d_in[3];
    const float* Wo = (const float*)d_in[4];
    float* U = (float*)d_out;
    kw_kernel<<<dim3(4096), dim3(256), 0, stream>>>(x, Wq, Wk, U);         // writes U
    kh_kernel<<<dim3(2048), dim3(256), 0, stream>>>(x, Wq, Wk, U);         // U +=
    kd_kernel<<<dim3(2048), dim3(256), 0, stream>>>(x, Wq, Wk, Wv, Wo, U); // += proj + x
}

// Round 6
// 379.541 us; speedup vs baseline: 2.1682x; 1.1371x over previous
//
#include <hip/hip_runtime.h>

// Axial multi-dimensional self-attention, B=1, C=32, D=32, H=128, W=128, fp32.
// Algebra: S = X^T M X (M = scale*Wq^T*Wk), P = softmax_rows(S), U = X P^T,
//          out = (Wo Wv) (U_D + U_H + U_W) + x.
// kw/kh: MFMA slice engine (split-bf16 scores, bf16 P)  [validated R5].
// kd: MFMA L=32 engine (2 slices/wave, wave-private LDS slots) fused with the
//     split-bf16 projection epilogue + residual.

#define C_ 32
#define D_ 32
#define H_ 128
#define W_ 128
#define SC (D_*H_*W_)   // 524288
#define SD (H_*W_)      // 16384
#define SH (W_)         // 128
#define SCALE 0.17677669529663687f

typedef __attribute__((ext_vector_type(8))) short short8;   // 8 bf16 (4 VGPR)
typedef __attribute__((ext_vector_type(4))) short short4v;  // 4 bf16
typedef __attribute__((ext_vector_type(2))) short short2v;  // 2 bf16
typedef __attribute__((ext_vector_type(4))) float f32x4;

#define MFMA16(a,b,c) __builtin_amdgcn_mfma_f32_16x16x32_bf16(a,b,c,0,0,0)

__device__ __forceinline__ int xcd_swz(int bid, int nwg) {
    int chunk = nwg >> 3;
    return (bid & 7) * chunk + (bid >> 3);
}
__device__ __forceinline__ short bf16_trunc(float f) {
    return (short)(__float_as_uint(f) >> 16);
}
__device__ __forceinline__ short bf16_rtne(float f) {
    unsigned u = __float_as_uint(f);
    unsigned r = u + 0x7FFFu + ((u >> 16) & 1u);
    return (short)(r >> 16);
}
__device__ __forceinline__ float bf16_tof(short s) {
    return __uint_as_float(((unsigned)(unsigned short)s) << 16);
}
// two ds_read_b64 (8B-aligned) -> short8
__device__ __forceinline__ short8 ld8_b64x2(const short* p) {
    short4v a = *(const short4v*)p;
    short4v b = *(const short4v*)(p + 4);
    short8 o;
    o[0]=a[0]; o[1]=a[1]; o[2]=a[2]; o[3]=a[3];
    o[4]=b[0]; o[5]=b[1]; o[6]=b[2]; o[7]=b[3];
    return o;
}

// split-bf16 M = SCALE * Wq^T Wk
__device__ __forceinline__ void compute_Mbf(const float* __restrict__ Wq,
                                            const float* __restrict__ Wk,
                                            short* Mh, short* Ml) {
    for (int o = threadIdx.x; o < 1024; o += 256) {
        int a = o >> 5, b = o & 31;
        float acc = 0.f;
        #pragma unroll
        for (int m = 0; m < 32; ++m) acc += Wq[m*32+a] * Wk[m*32+b];
        acc *= SCALE;
        short h = bf16_trunc(acc);
        Mh[o] = h;
        Ml[o] = bf16_trunc(acc - bf16_tof(h));
    }
}
// split-bf16 Ps = Wo * Wv
__device__ __forceinline__ void compute_Pbf(const float* __restrict__ Wv,
                                            const float* __restrict__ Wo,
                                            short* Ph, short* Pl) {
    for (int o = threadIdx.x; o < 1024; o += 256) {
        int oo = o >> 5, c = o & 31;
        float acc = 0.f;
        #pragma unroll
        for (int m = 0; m < 32; ++m) acc += Wo[oo*32+m] * Wv[m*32+c];
        short h = bf16_trunc(acc);
        Ph[o] = h;
        Pl[o] = bf16_trunc(acc - bf16_tof(h));
    }
}

// ---------------- MFMA slice engine: one L=128 slice (kw/kh) ----------------
#define TT_STRIDE 40
#define XH_STRIDE 136
#define P_STRIDE  136
#define R_BYTES   36864

__device__ __forceinline__ void slice_engine(
        const float* Xf, const short* Mh, const short* Ml,
        short* Tt_h, short* Tt_l, short* P, short* Xh,
        f32x4 uacc[2][2])
{
    const int t = threadIdx.x;
    const int wv = t >> 6, l = t & 63, hi = l >> 4, r = l & 15;
    const int qb = wv * 32;

    #pragma unroll
    for (int k = 0; k < 8; ++k) {
        int idx = t + k*256;
        int u2 = idx & 63, c = idx >> 6;
        float2 v = *(const float2*)&Xf[c*128 + u2*2];
        short2v h; h[0] = bf16_rtne(v.x); h[1] = bf16_rtne(v.y);
        *(short2v*)&Xh[c*XH_STRIDE + u2*2] = h;
    }

    short8 xh_[2], xl_[2];
    #pragma unroll
    for (int nt = 0; nt < 2; ++nt) {
        int u = qb + nt*16 + r;
        #pragma unroll
        for (int j = 0; j < 8; ++j) {
            float f = Xf[(hi*8 + j)*128 + u];
            short h = bf16_trunc(f);
            xh_[nt][j] = h; xl_[nt][j] = bf16_trunc(f - bf16_tof(h));
        }
    }

    short8 mah[2], mal[2];
    #pragma unroll
    for (int mt = 0; mt < 2; ++mt) {
        mah[mt] = *(const short8*)&Mh[(r + 16*mt)*32 + hi*8];
        mal[mt] = *(const short8*)&Ml[(r + 16*mt)*32 + hi*8];
    }
    f32x4 tacc[2][2] = {};
    #pragma unroll
    for (int nt = 0; nt < 2; ++nt) {
        #pragma unroll
        for (int mt = 0; mt < 2; ++mt) {
            tacc[mt][nt] = MFMA16(mah[mt], xh_[nt], tacc[mt][nt]);
            tacc[mt][nt] = MFMA16(mah[mt], xl_[nt], tacc[mt][nt]);
            tacc[mt][nt] = MFMA16(mal[mt], xh_[nt], tacc[mt][nt]);
        }
    }
    #pragma unroll
    for (int mt = 0; mt < 2; ++mt)
    #pragma unroll
    for (int nt = 0; nt < 2; ++nt) {
        int u = qb + nt*16 + r;
        #pragma unroll
        for (int rp = 0; rp < 2; ++rp) {
            int c0 = 16*mt + 4*hi + 2*rp;
            float f0 = tacc[mt][nt][2*rp], f1 = tacc[mt][nt][2*rp+1];
            short h0 = bf16_trunc(f0), h1 = bf16_trunc(f1);
            short2v vh; vh[0] = h0; vh[1] = h1;
            *(short2v*)&Tt_h[u*TT_STRIDE + c0] = vh;
            short2v vl; vl[0] = bf16_trunc(f0 - bf16_tof(h0));
            vl[1] = bf16_trunc(f1 - bf16_tof(h1));
            *(short2v*)&Tt_l[u*TT_STRIDE + c0] = vl;
        }
    }
    __syncthreads();

    f32x4 sacc[2][8] = {};
    #pragma unroll
    for (int nt = 0; nt < 8; ++nt) {
        short8 th = *(const short8*)&Tt_h[(nt*16 + r)*TT_STRIDE + hi*8];
        short8 tl = *(const short8*)&Tt_l[(nt*16 + r)*TT_STRIDE + hi*8];
        #pragma unroll
        for (int qt = 0; qt < 2; ++qt) {
            sacc[qt][nt] = MFMA16(xh_[qt], th, sacc[qt][nt]);
            sacc[qt][nt] = MFMA16(xh_[qt], tl, sacc[qt][nt]);
            sacc[qt][nt] = MFMA16(xl_[qt], th, sacc[qt][nt]);
        }
    }
    float rls[2][4];
    #pragma unroll
    for (int qt = 0; qt < 2; ++qt)
    #pragma unroll
    for (int reg = 0; reg < 4; ++reg) {
        float m = sacc[qt][0][reg];
        #pragma unroll
        for (int nt = 1; nt < 8; ++nt) m = fmaxf(m, sacc[qt][nt][reg]);
        m = fmaxf(m, __shfl_xor(m, 1));
        m = fmaxf(m, __shfl_xor(m, 2));
        m = fmaxf(m, __shfl_xor(m, 4));
        m = fmaxf(m, __shfl_xor(m, 8));
        float s = 0.f;
        #pragma unroll
        for (int nt = 0; nt < 8; ++nt) {
            float e = __expf(sacc[qt][nt][reg] - m);
            sacc[qt][nt][reg] = e; s += e;
        }
        s += __shfl_xor(s, 1);
        s += __shfl_xor(s, 2);
        s += __shfl_xor(s, 4);
        s += __shfl_xor(s, 8);
        rls[qt][reg] = 1.f / s;
    }
    __syncthreads();
    #pragma unroll
    for (int qt = 0; qt < 2; ++qt)
    #pragma unroll
    for (int reg = 0; reg < 4; ++reg) {
        int q = qb + 16*qt + 4*hi + reg;
        float rl = rls[qt][reg];
        #pragma unroll
        for (int nt = 0; nt < 8; ++nt)
            P[q*P_STRIDE + nt*16 + r] = bf16_rtne(sacc[qt][nt][reg] * rl);
    }
    __syncthreads();

    #pragma unroll
    for (int kt = 0; kt < 4; ++kt) {
        short8 xa[2], pb[2];
        #pragma unroll
        for (int mt = 0; mt < 2; ++mt)
            xa[mt] = *(const short8*)&Xh[(r + 16*mt)*XH_STRIDE + hi*8 + kt*32];
        #pragma unroll
        for (int nt = 0; nt < 2; ++nt)
            pb[nt] = *(const short8*)&P[(qb + 16*nt + r)*P_STRIDE + hi*8 + kt*32];
        #pragma unroll
        for (int mt = 0; mt < 2; ++mt)
        #pragma unroll
        for (int nt = 0; nt < 2; ++nt)
            uacc[mt][nt] = MFMA16(xa[mt], pb[nt], uacc[mt][nt]);
    }
}

// ---------------- W-axis: slice (d,h), coalesced ----------------------------
__global__ __launch_bounds__(256) void kw_kernel(const float* __restrict__ x,
        const float* __restrict__ Wq, const float* __restrict__ Wk,
        float* __restrict__ U) {
    __shared__ __align__(16) char Rr[R_BYTES];
    __shared__ __align__(16) short Xh[32*XH_STRIDE];
    __shared__ __align__(16) short MhS[1024], MlS[1024];
    float* Xf = (float*)Rr;
    short* Tt_h = (short*)(Rr + 16384);
    short* Tt_l = (short*)(Rr + 26624);
    short* P = (short*)Rr;
    int bid = xcd_swz(blockIdx.x, gridDim.x);
    int d = bid >> 7, h = bid & 127;
    int t = threadIdx.x;
    compute_Mbf(Wq, Wk, MhS, MlS);
    const float* xs = x + d*SD + h*SH;
    #pragma unroll
    for (int k = 0; k < 4; ++k) {
        int idx = t + k*256;
        int c = idx >> 5, u4 = idx & 31;
        *(float4*)&Xf[c*128 + u4*4] = *(const float4*)&xs[c*SC + u4*4];
    }
    __syncthreads();
    f32x4 uacc[2][2] = {};
    slice_engine(Xf, MhS, MlS, Tt_h, Tt_l, P, Xh, uacc);
    const int wv = t >> 6, l = t & 63, hi = l >> 4, r = l & 15;
    float* Uo = U + d*SD + h*SH;
    #pragma unroll
    for (int mt = 0; mt < 2; ++mt)
    #pragma unroll
    for (int nt = 0; nt < 2; ++nt)
    #pragma unroll
    for (int reg = 0; reg < 4; ++reg) {
        int c = 16*mt + 4*hi + reg;
        int q = wv*32 + 16*nt + r;
        Uo[c*SC + q] = uacc[mt][nt][reg];   // first axis: plain store
    }
}

// ---------------- H-axis: slices (d, w-pair) --------------------------------
__global__ __launch_bounds__(256) void kh_kernel(const float* __restrict__ x,
        const float* __restrict__ Wq, const float* __restrict__ Wk,
        float* __restrict__ U) {
    __shared__ __align__(16) char Rr[R_BYTES];
    __shared__ __align__(16) float Xf1[32*128];
    __shared__ __align__(16) short Xh[32*XH_STRIDE];
    __shared__ __align__(16) short MhS[1024], MlS[1024];
    float* Xf0 = (float*)Rr;
    short* Tt_h = (short*)(Rr + 16384);
    short* Tt_l = (short*)(Rr + 26624);
    short* P = (short*)Rr;
    int bid = xcd_swz(blockIdx.x, gridDim.x);   // same-d siblings share an XCD
    int d = bid >> 6, w0 = (bid & 63) * 2;
    int t = threadIdx.x;
    compute_Mbf(Wq, Wk, MhS, MlS);
    const float* xs = x + d*SD + w0;
    #pragma unroll
    for (int k = 0; k < 16; ++k) {
        int idx = t + k*256;
        int c = idx >> 7, g = idx & 127;
        float2 v = *(const float2*)&xs[c*SC + g*SH];
        Xf0[c*128+g] = v.x;
        Xf1[c*128+g] = v.y;
    }
    __syncthreads();
    f32x4 u0[2][2] = {}, u1[2][2] = {};
    slice_engine(Xf0, MhS, MlS, Tt_h, Tt_l, P, Xh, u0);
    __syncthreads();
    slice_engine(Xf1, MhS, MlS, Tt_h, Tt_l, P, Xh, u1);
    const int wv = t >> 6, l = t & 63, hi = l >> 4, r = l & 15;
    float* Uo = U + d*SD + w0;
    #pragma unroll
    for (int mt = 0; mt < 2; ++mt)
    #pragma unroll
    for (int nt = 0; nt < 2; ++nt)
    #pragma unroll
    for (int reg = 0; reg < 4; ++reg) {
        int c = 16*mt + 4*hi + reg;
        int q = wv*32 + 16*nt + r;
        float2* p = (float2*)&Uo[c*SC + q*SH];
        float2 v = *p;
        v.x += u0[mt][nt][reg];
        v.y += u1[mt][nt][reg];
        *p = v;
    }
}

// ---------------- D-axis (L=32) MFMA engine + fused projection epilogue -----
// Block: 8 d-slices (h, w0..w0+7), 4 waves, wave wv owns slices {wv, wv+4}.
// LDS: Mh/Ml 4KB | Psh/Psl 4KB | Xh/Xl [8][32][36] 36KB |
//      R 33792B = Tt_h[4][32][40] (10240) + Tt_l (10240) + Pp[4][32][36] (9216)
//                 all wave-private slots; later overlaid by u_lds f32 [32][264].
#define XJ 1152        // 32*36 shorts per slice plane
#define KD_TTS 40
#define KD_PS  36
__global__ __launch_bounds__(256, 2) void kd_kernel(const float* __restrict__ x,
        const float* __restrict__ Wq, const float* __restrict__ Wk,
        const float* __restrict__ Wv, const float* __restrict__ Wo,
        float* __restrict__ UO) {
    __shared__ __align__(16) short Mh[1024], Ml[1024], Psh[1024], Psl[1024];
    __shared__ __align__(16) short Xh[8*XJ], Xl[8*XJ];
    __shared__ __align__(16) char Rr[33792];
    short* Tt_h = (short*)Rr;             // [4][32][40]
    short* Tt_l = (short*)(Rr + 10240);   // [4][32][40]
    short* Pp   = (short*)(Rr + 20480);   // [4][32][36]
    float* u_lds = (float*)Rr;            // [32][264] after all slots consumed

    int bid = xcd_swz(blockIdx.x, gridDim.x);
    int h = bid >> 4, w0 = (bid & 15) * 8;
    int t = threadIdx.x;
    const int wv = t >> 6, l = t & 63, hi = l >> 4, r = l & 15;

    compute_Mbf(Wq, Wk, Mh, Ml);
    compute_Pbf(Wv, Wo, Psh, Psl);

    // stage x -> split-bf16 Xh/Xl [j][c][d]
    const float* xs = x + h*SH + w0;
    #pragma unroll
    for (int k = 0; k < 8; ++k) {
        int o = t + k*256;
        int j4 = o & 1, d = (o >> 1) & 31, c = o >> 6;
        float4 v = *(const float4*)(xs + c*SC + d*SD + j4*4);
        float fr[4] = {v.x, v.y, v.z, v.w};
        #pragma unroll
        for (int i = 0; i < 4; ++i) {
            short hh = bf16_trunc(fr[i]);
            Xh[((j4*4+i)*32 + c)*KD_PS + d] = hh;
            Xl[((j4*4+i)*32 + c)*KD_PS + d] = bf16_trunc(fr[i] - bf16_tof(hh));
        }
    }
    __syncthreads();                                  // (1) staging visible

    short8 mah[2], mal[2], pah[2], pal[2];
    #pragma unroll
    for (int mt = 0; mt < 2; ++mt) {
        mah[mt] = *(const short8*)&Mh[(mt*16 + r)*32 + hi*8];
        mal[mt] = *(const short8*)&Ml[(mt*16 + r)*32 + hi*8];
        pah[mt] = *(const short8*)&Psh[(mt*16 + r)*32 + hi*8];
        pal[mt] = *(const short8*)&Psl[(mt*16 + r)*32 + hi*8];
    }

    f32x4 uacc[2][2][2] = {};   // [pass][mt(c)][nt(d)]
    float4 upre[8];

    #pragma unroll
    for (int ps = 0; ps < 2; ++ps) {
        int j = ps*4 + wv;
        const short* Xhj = &Xh[j*XJ];
        const short* Xlj = &Xl[j*XJ];
        // column fragments (T-B and S-A roles, identical lane layout)
        short8 xph[2], xpl[2];
        #pragma unroll
        for (int et = 0; et < 2; ++et)
        #pragma unroll
        for (int jj = 0; jj < 8; ++jj) {
            int c = hi*8 + jj;
            xph[et][jj] = Xhj[c*KD_PS + et*16 + r];
            xpl[et][jj] = Xlj[c*KD_PS + et*16 + r];
        }
        // T = M*X (3-MFMA split)
        f32x4 tacc[2][2] = {};
        #pragma unroll
        for (int et = 0; et < 2; ++et)
        #pragma unroll
        for (int mt = 0; mt < 2; ++mt) {
            tacc[mt][et] = MFMA16(mah[mt], xph[et], tacc[mt][et]);
            tacc[mt][et] = MFMA16(mah[mt], xpl[et], tacc[mt][et]);
            tacc[mt][et] = MFMA16(mal[mt], xph[et], tacc[mt][et]);
        }
        // Tt[e][c] split, wave-private slot
        int tb = wv*32*KD_TTS;
        #pragma unroll
        for (int mt = 0; mt < 2; ++mt)
        #pragma unroll
        for (int et = 0; et < 2; ++et) {
            int e = et*16 + r;
            #pragma unroll
            for (int rp = 0; rp < 2; ++rp) {
                int c0 = mt*16 + hi*4 + rp*2;
                float f0 = tacc[mt][et][rp*2], f1 = tacc[mt][et][rp*2+1];
                short h0 = bf16_trunc(f0), h1 = bf16_trunc(f1);
                short2v vh; vh[0] = h0; vh[1] = h1;
                *(short2v*)&Tt_h[tb + e*KD_TTS + c0] = vh;
                short2v vl; vl[0] = bf16_trunc(f0 - bf16_tof(h0));
                vl[1] = bf16_trunc(f1 - bf16_tof(h1));
                *(short2v*)&Tt_l[tb + e*KD_TTS + c0] = vl;
            }
        }
        // S = X^T T (3-MFMA split), own slot only (no barrier needed)
        f32x4 sacc[2][2] = {};
        #pragma unroll
        for (int et = 0; et < 2; ++et) {
            short8 th = *(const short8*)&Tt_h[tb + (et*16 + r)*KD_TTS + hi*8];
            short8 tl = *(const short8*)&Tt_l[tb + (et*16 + r)*KD_TTS + hi*8];
            #pragma unroll
            for (int qt = 0; qt < 2; ++qt) {
                sacc[qt][et] = MFMA16(xph[qt], th, sacc[qt][et]);
                sacc[qt][et] = MFMA16(xph[qt], tl, sacc[qt][et]);
                sacc[qt][et] = MFMA16(xpl[qt], th, sacc[qt][et]);
            }
        }
        // softmax over e (row d = qt*16+hi*4+reg, col e = et*16+r)
        int pb = wv*32*KD_PS;
        #pragma unroll
        for (int qt = 0; qt < 2; ++qt)
        #pragma unroll
        for (int reg = 0; reg < 4; ++reg) {
            float m = fmaxf(sacc[qt][0][reg], sacc[qt][1][reg]);
            m = fmaxf(m, __shfl_xor(m, 1));
            m = fmaxf(m, __shfl_xor(m, 2));
            m = fmaxf(m, __shfl_xor(m, 4));
            m = fmaxf(m, __shfl_xor(m, 8));
            float e0 = __expf(sacc[qt][0][reg] - m);
            float e1 = __expf(sacc[qt][1][reg] - m);
            float s = e0 + e1;
            s += __shfl_xor(s, 1);
            s += __shfl_xor(s, 2);
            s += __shfl_xor(s, 4);
            s += __shfl_xor(s, 8);
            float rl = 1.f / s;
            int d = qt*16 + hi*4 + reg;
            Pp[pb + d*KD_PS + 0*16 + r] = bf16_rtne(e0 * rl);
            Pp[pb + d*KD_PS + 1*16 + r] = bf16_rtne(e1 * rl);
        }
        // U = X * P^T (bf16), own slot
        #pragma unroll
        for (int mt = 0; mt < 2; ++mt) {
            short8 xa = ld8_b64x2(&Xhj[(mt*16 + r)*KD_PS + hi*8]);
            #pragma unroll
            for (int nt = 0; nt < 2; ++nt) {
                short8 pbf = ld8_b64x2(&Pp[pb + (nt*16 + r)*KD_PS + hi*8]);
                uacc[ps][mt][nt] = MFMA16(xa, pbf, uacc[ps][mt][nt]);
            }
        }
        // prefetch UO into registers after pass 0 (consumed post-barrier)
        if (ps == 0) {
            #pragma unroll
            for (int k = 0; k < 8; ++k) {
                int o = t + k*256;
                int j4 = o & 1, d = (o >> 1) & 31, c = o >> 6;
                upre[k] = *(const float4*)(UO + c*SC + d*SD + h*SH + w0 + j4*4);
            }
        }
    }
    __syncthreads();                                  // (2) all Tt/Pp reads done
    // dump prefetched UO -> u_lds [c][s], s = d*8 + j
    #pragma unroll
    for (int k = 0; k < 8; ++k) {
        int o = t + k*256;
        int j4 = o & 1, d = (o >> 1) & 31, c = o >> 6;
        *(float4*)&u_lds[c*264 + d*8 + j4*4] = upre[k];
    }
    __syncthreads();                                  // (3) u_lds filled
    // accumulate U_d (wave-unique (d,j) slots -> no collisions)
    #pragma unroll
    for (int ps = 0; ps < 2; ++ps)
    #pragma unroll
    for (int mt = 0; mt < 2; ++mt)
    #pragma unroll
    for (int nt = 0; nt < 2; ++nt)
    #pragma unroll
    for (int reg = 0; reg < 4; ++reg) {
        int c = mt*16 + hi*4 + reg;
        u_lds[c*264 + (nt*16 + r)*8 + ps*4 + wv] += uacc[ps][mt][nt][reg];
    }
    __syncthreads();                                  // (4) u complete
    // epilogue: out = Ps*u + x over 256 sites, wave owns s in [wv*64, wv*64+64)
    f32x4 eacc[2][4] = {};
    #pragma unroll
    for (int nt = 0; nt < 4; ++nt) {
        short8 bh, bl;
        #pragma unroll
        for (int jj = 0; jj < 8; ++jj) {
            float f = u_lds[(hi*8 + jj)*264 + wv*64 + nt*16 + r];
            short hh = bf16_trunc(f);
            bh[jj] = hh; bl[jj] = bf16_trunc(f - bf16_tof(hh));
        }
        #pragma unroll
        for (int mt = 0; mt < 2; ++mt) {
            eacc[mt][nt] = MFMA16(pah[mt], bh, eacc[mt][nt]);
            eacc[mt][nt] = MFMA16(pah[mt], bl, eacc[mt][nt]);
            eacc[mt][nt] = MFMA16(pal[mt], bh, eacc[mt][nt]);
        }
    }
    #pragma unroll
    for (int mt = 0; mt < 2; ++mt)
    #pragma unroll
    for (int nt = 0; nt < 4; ++nt)
    #pragma unroll
    for (int reg = 0; reg < 4; ++reg) {
        int o = mt*16 + hi*4 + reg;
        int s = wv*64 + nt*16 + r;
        int addr = o*SC + (s >> 3)*SD + h*SH + w0 + (s & 7);
        UO[addr] = eacc[mt][nt][reg] + x[addr];
    }
}

extern "C" void kernel_launch(void* const* d_in, const int* in_sizes, int n_in,
                              void* d_out, int out_size, void* d_ws, size_t ws_size,
                              hipStream_t stream) {
    (void)in_sizes; (void)n_in; (void)out_size; (void)d_ws; (void)ws_size;
    const float* x  = (const float*)d_in[0];
    const float* Wq = (const float*)d_in[1];
    const float* Wk = (const float*)d_in[2];
    const float* Wv = (const float*)d_in[3];
    const float* Wo = (const float*)d_in[4];
    float* U = (float*)d_out;
    kw_kernel<<<dim3(4096), dim3(256), 0, stream>>>(x, Wq, Wk, U);         // writes U
    kh_kernel<<<dim3(2048), dim3(256), 0, stream>>>(x, Wq, Wk, U);         // U +=
    kd_kernel<<<dim3(2048), dim3(256), 0, stream>>>(x, Wq, Wk, Wv, Wo, U); // += proj + x
}